// Round 17
// baseline (251.579 us; speedup 1.0000x reference)
//
#include <hip/hip_runtime.h>
#include <math.h>

#define FIELD 2097152   // 32*512*128
#define NSEQ  4096      // 32*128 sequences
#define MAGIC 0x5A5A5A5Au   // != 0xAAAAAAAA ws poison

typedef float f2 __attribute__((ext_vector_type(2)));   // (re, im) -> VGPR pair

__device__ __forceinline__ f2 swp(f2 a) { return __builtin_shufflevector(a, a, 1, 0); }
__device__ __forceinline__ f2 conjf2(f2 a) { return (f2){a.x, -a.y}; }
// multiply by (c + i s), with ns = (-s, s): 1 pk_mul + 1 pk_fma (swap -> op_sel)
__device__ __forceinline__ f2 cmulp(f2 a, float c, f2 ns)  { return c * a + ns * swp(a); }
// multiply by (c - i s)
__device__ __forceinline__ f2 cmulpc(f2 a, float c, f2 ns) { return c * a - ns * swp(a); }
// a + i*b  /  a - i*b
__device__ __forceinline__ f2 addi(f2 a, f2 b) { return a + (f2){-1.0f, 1.0f} * swp(b); }
__device__ __forceinline__ f2 subi(f2 a, f2 b) { return a + (f2){1.0f, -1.0f} * swp(b); }

// ---- xor-lane exchange: DPP (VALU-speed) for h in {1,2,4,8}; bpermute-based
// ---- __shfl_xor only for cross-row h in {16,32}. All 64 lanes active.
template<int CTRL>
__device__ __forceinline__ float dpp_f(float v) {
  return __int_as_float(__builtin_amdgcn_update_dpp(
      __float_as_int(v), __float_as_int(v), CTRL, 0xF, 0xF, true));
}
template<int CTRL>
__device__ __forceinline__ float dpp0_f(float v) {   // old=0, invalid lanes -> 0
  return __int_as_float(__builtin_amdgcn_update_dpp(
      0, __float_as_int(v), CTRL, 0xF, 0xF, true));
}
template<int H>
__device__ __forceinline__ float xlane(float v) {
  if constexpr (H == 1)      return dpp_f<0xB1>(v);    // quad_perm [1,0,3,2] = xor1
  else if constexpr (H == 2) return dpp_f<0x4E>(v);    // quad_perm [2,3,0,1] = xor2
  else if constexpr (H == 4) return dpp_f<0x141>(dpp_f<0x1B>(v)); // xor7 o xor3 = xor4
  else if constexpr (H == 8) return dpp_f<0x128>(v);   // row_ror:8 = xor8
  else return __shfl_xor(v, H, 64);
}
template<int H>
__device__ __forceinline__ f2 xlane2(f2 v) {
  return (f2){xlane<H>(v.x), xlane<H>(v.y)};
}
__device__ __forceinline__ f2 shfl2(f2 v, int l) {
  return (f2){__shfl(v.x, l, 64), __shfl(v.y, l, 64)};
}
__device__ __forceinline__ float bcast0(float v) {
  return __int_as_float(__builtin_amdgcn_readfirstlane(__float_as_int(v)));
}
// 64-lane sum, zero DS ops: row_shr prefix adds + row_bcast15/31.
__device__ __forceinline__ float wave_sum(float v) {
  v += dpp0_f<0x111>(v);   // row_shr:1
  v += dpp0_f<0x112>(v);   // row_shr:2
  v += dpp0_f<0x114>(v);   // row_shr:4
  v += dpp0_f<0x118>(v);   // row_shr:8
  v += dpp0_f<0x142>(v);   // row_bcast15
  v += dpp0_f<0x143>(v);   // row_bcast31 -> lane 63 holds total
  return __int_as_float(__builtin_amdgcn_readlane(__float_as_int(v), 63));
}

__device__ __forceinline__ void fft4_fwd(f2* v) {
  f2 t0 = v[0] + v[2], t1 = v[0] - v[2];
  f2 t2 = v[1] + v[3], t3 = v[1] - v[3];
  v[0] = t0 + t2; v[2] = t0 - t2;
  v[1] = subi(t1, t3);
  v[3] = addi(t1, t3);
}
__device__ __forceinline__ void fft4_inv(f2* v) {
  f2 t0 = v[0] + v[2], t1 = v[0] - v[2];
  f2 t2 = v[1] + v[3], t3 = v[1] - v[3];
  v[0] = t0 + t2; v[2] = t0 - t2;
  v[1] = addi(t1, t3);
  v[3] = subi(t1, t3);
}

// Butterfly stages with LANE-MASKED twiddles (lo lanes hold W=(1,0): no
// cndmask selects anywhere). sg = +1 lo / -1 hi.
template<int H>
__device__ __forceinline__ void fwd_stage(f2* v, float wr, f2 wn, float sg) {
#pragma unroll
  for (int b = 0; b < 4; ++b) {
    f2 p = xlane2<H>(v[b]);
    f2 t = sg * v[b] + p;          // lo: v+p ; hi: p-v
    v[b] = cmulp(t, wr, wn);       // lo: *1 ; hi: *e^{-i th}
  }
}
template<int H>
__device__ __forceinline__ void inv_stage(f2* v, float wr, f2 wn, float sg) {
#pragma unroll
  for (int b = 0; b < 4; ++b) {
    f2 u = cmulpc(v[b], wr, wn);   // lo: v ; hi: v*e^{+i th} (conj W)
    f2 p = xlane2<H>(u);
    v[b] = sg * u + p;             // lo: u+p ; hi: p-u
  }
}

// 256-point FFT: time n = 64a+lane (slot a) <-> freq k = 4*rev6(lane)+b.
__device__ __forceinline__ void fft256_fwd(f2* v,
                                           const float* twFc, const f2* twFn,
                                           const float* wrS, const f2* wnS,
                                           const float* sgS) {
  fft4_fwd(v);
#pragma unroll
  for (int b = 1; b < 4; ++b) v[b] = cmulp(v[b], twFc[b-1], twFn[b-1]);
  fwd_stage<32>(v, wrS[0], wnS[0], sgS[0]);
  fwd_stage<16>(v, wrS[1], wnS[1], sgS[1]);
  fwd_stage<8> (v, wrS[2], wnS[2], sgS[2]);
  fwd_stage<4> (v, wrS[3], wnS[3], sgS[3]);
  fwd_stage<2> (v, wrS[4], wnS[4], sgS[4]);
  fwd_stage<1> (v, wrS[5], wnS[5], sgS[5]);
}

__device__ __forceinline__ void ifft256(f2* v,
                                        const float* twFc, const f2* twFn,
                                        const float* wrS, const f2* wnS,
                                        const float* sgS) {
  inv_stage<1> (v, wrS[5], wnS[5], sgS[5]);
  inv_stage<2> (v, wrS[4], wnS[4], sgS[4]);
  inv_stage<4> (v, wrS[3], wnS[3], sgS[3]);
  inv_stage<8> (v, wrS[2], wnS[2], sgS[2]);
  inv_stage<16>(v, wrS[1], wnS[1], sgS[1]);
  inv_stage<32>(v, wrS[0], wnS[0], sgS[0]);
#pragma unroll
  for (int b = 1; b < 4; ++b) v[b] = cmulpc(v[b], twFc[b-1], twFn[b-1]);
  fft4_inv(v);
}

// Half-spectrum S[0..255] (+ real scalar S256) -> packed Z for ifft256.
__device__ __forceinline__ void half_to_z(f2* S, float S256,
                                          const float* twHc, const f2* twHn,
                                          int lane, int pl0, int plx) {
  f2 P[4];
  P[0] = shfl2(S[0], pl0);
#pragma unroll
  for (int b = 1; b < 4; ++b) P[b] = shfl2(S[4 - b], plx);
  P[0] = (lane == 0) ? (f2){S256, 0.0f} : P[0];
#pragma unroll
  for (int b = 0; b < 4; ++b) {
    f2 cP = conjf2(P[b]);
    f2 A = 0.5f * (S[b] + cP);
    f2 B = 0.5f * (S[b] - cP);
    f2 Bt = cmulp(B, twHc[b], twHn[b]);   // B * e^{+i th}
    S[b] = addi(A, Bt);
  }
}

// Per-bin mode update exploiting Hermitian symmetry (no cross-lane ops).
__device__ __forceinline__ void mode_update4(const f2* X, const f2* V, f2* U,
                                             const float* lam1, const float* lam2,
                                             float om, float f0) {
#pragma unroll
  for (int b = 0; b < 4; ++b) {
    float f = f0 + (float)b * (1.0f / 512.0f);
    float dfp = f - om;
    float dfm = f + om;
    float gp = __builtin_amdgcn_rcpf(fmaf(1600.0f * dfp, dfp, 1.0f));
    float gm = __builtin_amdgcn_rcpf(fmaf(1600.0f * dfm, dfm, 1.0f));
    float gs = 0.5f * (gp + gm);
    f2 D = X[b] - V[b];
    float lt = 0.25f * fmaf(lam1[b], gp, lam2[b] * gm);
    U[b] = gs * D + (f2){lt, 0.0f};
  }
}

// One wave per (b,d) sequence. Fully fused single kernel: hand-rolled
// release/acquire flag sync replaces round-14's rejected cooperative launch.
// Safe because grid = 1024 blocks = exactly 4 blocks/CU x 256 CU with
// waves_per_eu(4,4) pinned — whole grid co-resident (verified round 6:
// single-pass timing at this exact config). Flags live in d_ws, which the
// harness re-poisons to 0xAA before every launch (self-resetting).
__global__ __attribute__((amdgpu_flat_work_group_size(256, 256),
                          amdgpu_waves_per_eu(4, 4),
                          amdgpu_num_vgpr(96)))
void vmd_kernel(const float* __restrict__ x, float* __restrict__ out,
                float* __restrict__ ws) {
  __shared__ float stage[4 * 512];    // [seq][n]; x resident during loop, reused for out
  __shared__ float ldsLam[4 * 512];   // psi-permuted lambda per wave
  __shared__ float oms[8];
  __shared__ float flagS;

  const int tid = threadIdx.x;
  const int wv = tid >> 6;
  const int lane = tid & 63;
  const int w = (blockIdx.x >> 3) + ((blockIdx.x & 7) << 7);   // XCD swizzle
  const int bb = w >> 5;
  const int d0 = (4 * w) & 127;
  const int base4 = bb * 16384 + (d0 >> 2);
  float* lamLds = ldsLam + wv * 512;
  f2* stg2 = (f2*)stage + wv * 256;   // packed (even,odd) pair view of this seq

  const int rev = (int)(__brev((unsigned)lane) >> 26);           // rev6(lane)
  const float f0 = (float)rev * (1.0f / 128.0f);
  const int plx = lane ^ 63;
  const int pl0 = (int)(__brev((unsigned)((64 - rev) & 63)) >> 26);

  // Stage twiddles, lane-masked: lo lanes = identity (wr=1, wn=0).
  float wrS[6], sgS[6]; f2 wnS[6];
#pragma unroll
  for (int s = 0; s < 6; ++s) {
    const int h = 32 >> s;
    const bool hi = (lane & h) != 0;
    float th = (float)(lane & (h - 1)) * (3.14159265358979323846f / (float)h);
    float sn, cs; sincosf(th, &sn, &cs);
    wrS[s] = hi ? cs : 1.0f;                        // W = e^{-i th}
    wnS[s] = hi ? (f2){sn, -sn} : (f2){0.0f, 0.0f};
    sgS[s] = hi ? -1.0f : 1.0f;
  }
  float twFc[3]; f2 twFn[3];
#pragma unroll
  for (int b = 1; b < 4; ++b) {
    float th = (float)(lane * b) * 0.02454369260617026f;   // 2pi/256, e^{-i th}
    float sn, cs; sincosf(th, &sn, &cs);
    twFc[b-1] = cs; twFn[b-1] = (f2){sn, -sn};
  }
  float twHc[4]; f2 twHn[4];
#pragma unroll
  for (int b = 0; b < 4; ++b) {
    float th = (float)(4 * rev + b) * 0.01227184630308513f; // 2pi/512, e^{+i th}
    float sn, cs; sincosf(th, &sn, &cs);
    twHc[b] = cs; twHn[b] = (f2){-sn, sn};
  }

  // ---- load x: float4 (n, d0..d0+3) -> stage[seq][n]; zero lambda ----
  {
    const float4* x4 = (const float4*)x;
    float4 va = x4[base4 + tid * 32];
    float4 vb = x4[base4 + (tid + 256) * 32];
    stage[tid]        = va.x; stage[512 + tid]        = va.y;
    stage[1024 + tid] = va.z; stage[1536 + tid]       = va.w;
    stage[tid + 256]        = vb.x; stage[512 + tid + 256]  = vb.y;
    stage[1024 + tid + 256] = vb.z; stage[1536 + tid + 256] = vb.w;
#pragma unroll
    for (int j = 0; j < 8; ++j) ldsLam[tid * 8 + j] = 0.0f;
  }
  __syncthreads();

  // ---- initial FFT input straight from LDS (x stays resident in stage) ----
  f2 z[4];
#pragma unroll
  for (int a = 0; a < 4; ++a) z[a] = stg2[64 * a + lane];
  fft256_fwd(z, twFc, twFn, wrS, wnS, sgS);
  f2 X[4];
  float X256;
  {
    f2 P[4];
    P[0] = shfl2(z[0], pl0);
#pragma unroll
    for (int b = 1; b < 4; ++b) P[b] = shfl2(z[4 - b], plx);
    X256 = bcast0(z[0].x - z[0].y);
#pragma unroll
    for (int b = 0; b < 4; ++b) {
      f2 cP = conjf2(P[b]);
      f2 E = 0.5f * (z[b] + cP);
      f2 O = 0.5f * (f2){1.0f, -1.0f} * swp(z[b] - cP);   // -i*(z-cP)/2
      X[b] = E + cmulpc(O, twHc[b], twHn[b]);             // O * e^{-i th}
    }
  }

  f2 U0[4], U1[4], lam[4];
#pragma unroll
  for (int b = 0; b < 4; ++b) {
    U0[b] = (f2){0.0f, 0.0f}; U1[b] = (f2){0.0f, 0.0f};
    lam[b] = (f2){0.0f, 0.0f};
  }
  float U0_256 = 0.0f, U1_256 = 0.0f;
  float om0 = 0.0f, om1 = 0.0f;

  const int psiE = 256 * (lane & 1) + (lane >> 1);   // lambda write base

#pragma unroll 1
  for (int it = 0; it < 50; ++it) {
    float lam1[4], lam2[4];
#pragma unroll
    for (int b = 0; b < 4; ++b) lam1[b] = lamLds[128 * b + 64 + rev];
    lam2[0] = lamLds[64 - rev];
#pragma unroll
    for (int b = 1; b < 4; ++b) lam2[b] = lamLds[128 * (4 - b) + 63 - rev];
    float lam0 = lamLds[0];

    mode_update4(X, U1, U0, lam1, lam2, om0, f0);
    {
      float dm = 0.5f + om0;
      float gg = __builtin_amdgcn_rcpf(fmaf(1600.0f * dm, dm, 1.0f));
      U0_256 = (X256 - U1_256 + 0.5f * lam0) * gg;
    }
    mode_update4(X, U0, U1, lam1, lam2, om1, f0);
    {
      float dm = 0.5f + om1;
      float gg = __builtin_amdgcn_rcpf(fmaf(1600.0f * dm, dm, 1.0f));
      U1_256 = (X256 - U0_256 + 0.5f * lam0) * gg;
    }

    // omega: per-bin accumulate, then pure-DPP wave sums (zero DS ops)
    f2 s0 = (f2){0.0f, 0.0f}, s1 = (f2){0.0f, 0.0f};
#pragma unroll
    for (int b = 0; b < 4; ++b) {
      float f = f0 + (float)b * (1.0f / 512.0f);
      float p0 = fmaf(U0[b].x, U0[b].x, U0[b].y * U0[b].y);
      float p1 = fmaf(U1[b].x, U1[b].x, U1[b].y * U1[b].y);
      s0 = s0 + (f2){f * p0, p0};
      s1 = s1 + (f2){f * p1, p1};
    }
    float n0 = wave_sum(s0.x), d0s = wave_sum(s0.y);
    float n1 = wave_sum(s1.x), d1s = wave_sum(s1.y);
    om0 = n0 * __builtin_amdgcn_rcpf(d0s + 1e-7f);
    om1 = n1 * __builtin_amdgcn_rcpf(d1s + 1e-7f);

    if (it < 49) {   // last iteration's lambda is never consumed
#pragma unroll
      for (int b = 0; b < 4; ++b) z[b] = U0[b] + U1[b];
      float S256 = U0_256 + U1_256;
      half_to_z(z, S256, twHc, twHn, lane, pl0, plx);
      ifft256(z, twFc, twFn, wrS, wnS, sgS);
#pragma unroll
      for (int a = 0; a < 4; ++a) {
        f2 xa = stg2[64 * a + lane];               // x from LDS
        lam[a] = lam[a] + 0.001f * (xa - z[a] * (1.0f / 256.0f));
        lamLds[psiE + 32 * a]       = lam[a].x;
        lamLds[psiE + 32 * a + 128] = lam[a].y;
      }
      asm volatile("s_waitcnt lgkmcnt(0)" ::: "memory");
    }
  }

  // ---- fused ordering: publish per-block omega partials + release flag,
  // ---- spin on this batch's 32 flags, reduce, then direct swapped writes.
  if (lane == 0) { oms[2 * wv] = om0; oms[2 * wv + 1] = om1; }
  __syncthreads();
  unsigned* flags = (unsigned*)ws + 4096;   // 16 KB into ws
  if (tid == 0) {
    __hip_atomic_store(&ws[2 * w],     oms[0] + oms[2] + oms[4] + oms[6],
                       __ATOMIC_RELAXED, __HIP_MEMORY_SCOPE_AGENT);
    __hip_atomic_store(&ws[2 * w + 1], oms[1] + oms[3] + oms[5] + oms[7],
                       __ATOMIC_RELAXED, __HIP_MEMORY_SCOPE_AGENT);
    __hip_atomic_store(&flags[w], MAGIC, __ATOMIC_RELEASE,
                       __HIP_MEMORY_SCOPE_AGENT);
  }
  if (wv == 0) {
    const int j = lane & 31;               // lanes 32-63 duplicate lanes 0-31
    const unsigned* fb = flags + bb * 32;
    while (__hip_atomic_load(&fb[j], __ATOMIC_ACQUIRE,
                             __HIP_MEMORY_SCOPE_AGENT) != MAGIC) {
      __builtin_amdgcn_s_sleep(1);
    }
    float o0 = __hip_atomic_load(&ws[2 * (bb * 32 + j)],     __ATOMIC_RELAXED,
                                 __HIP_MEMORY_SCOPE_AGENT);
    float o1 = __hip_atomic_load(&ws[2 * (bb * 32 + j) + 1], __ATOMIC_RELAXED,
                                 __HIP_MEMORY_SCOPE_AGENT);
    o0 += xlane<16>(o0); o1 += xlane<16>(o1);   // 32-lane sums (halves dup)
    o0 += xlane<8>(o0);  o1 += xlane<8>(o1);
    o0 += xlane<4>(o0);  o1 += xlane<4>(o1);
    o0 += xlane<2>(o0);  o1 += xlane<2>(o1);
    o0 += xlane<1>(o0);  o1 += xlane<1>(o1);
    if (lane == 0) flagS = (o0 > o1) ? 1.0f : 0.0f;  // swap iff mean0 > mean1
  }
  __syncthreads();
  const bool sw = flagS > 0.5f;

  float4* o4 = (float4*)out;
  const int dstU0 = (sw ? 2 * FIELD : FIELD) / 4;   // U0 -> res if swapped
  const int dstU1 = (sw ? FIELD : 2 * FIELD) / 4;

  // zero this block's trend slice
#pragma unroll
  for (int r = 0; r < 2; ++r)
    o4[base4 + (tid + r * 256) * 32] = (float4){0.0f, 0.0f, 0.0f, 0.0f};

#pragma unroll
  for (int b = 0; b < 4; ++b) z[b] = U0[b];
  half_to_z(z, U0_256, twHc, twHn, lane, pl0, plx);
  ifft256(z, twFc, twFn, wrS, wnS, sgS);
  __syncthreads();   // all waves done reading x from stage
#pragma unroll
  for (int a = 0; a < 4; ++a) stg2[64 * a + lane] = z[a] * (1.0f / 256.0f);
  __syncthreads();
#pragma unroll
  for (int r = 0; r < 2; ++r) {
    const int n = tid + r * 256;
    float4 v;
    v.x = stage[n]; v.y = stage[512 + n]; v.z = stage[1024 + n]; v.w = stage[1536 + n];
    o4[dstU0 + base4 + n * 32] = v;
  }
  __syncthreads();
#pragma unroll
  for (int b = 0; b < 4; ++b) z[b] = U1[b];
  half_to_z(z, U1_256, twHc, twHn, lane, pl0, plx);
  ifft256(z, twFc, twFn, wrS, wnS, sgS);
#pragma unroll
  for (int a = 0; a < 4; ++a) stg2[64 * a + lane] = z[a] * (1.0f / 256.0f);
  __syncthreads();
#pragma unroll
  for (int r = 0; r < 2; ++r) {
    const int n = tid + r * 256;
    float4 v;
    v.x = stage[n]; v.y = stage[512 + n]; v.z = stage[1024 + n]; v.w = stage[1536 + n];
    o4[dstU1 + base4 + n * 32] = v;
  }
}

extern "C" void kernel_launch(void* const* d_in, const int* in_sizes, int n_in,
                              void* d_out, int out_size, void* d_ws, size_t ws_size,
                              hipStream_t stream) {
  (void)in_sizes; (void)n_in; (void)ws_size; (void)out_size;
  const float* x = (const float*)d_in[0];
  float* out = (float*)d_out;
  float* ws = (float*)d_ws;
  vmd_kernel<<<NSEQ / 4, 256, 0, stream>>>(x, out, ws);
}

// Round 18
// 231.807 us; speedup vs baseline: 1.0853x; 1.0853x over previous
//
#include <hip/hip_runtime.h>
#include <math.h>

#define FIELD 2097152   // 32*512*128
#define NSEQ  4096      // 32*128 sequences

typedef float f2 __attribute__((ext_vector_type(2)));   // (re, im) -> VGPR pair

__device__ __forceinline__ f2 swp(f2 a) { return __builtin_shufflevector(a, a, 1, 0); }
__device__ __forceinline__ f2 conjf2(f2 a) { return (f2){a.x, -a.y}; }
// multiply by (c + i s), with ns = (-s, s): 1 pk_mul + 1 pk_fma (swap -> op_sel)
__device__ __forceinline__ f2 cmulp(f2 a, float c, f2 ns)  { return c * a + ns * swp(a); }
// multiply by (c - i s)
__device__ __forceinline__ f2 cmulpc(f2 a, float c, f2 ns) { return c * a - ns * swp(a); }
// a + i*b  /  a - i*b
__device__ __forceinline__ f2 addi(f2 a, f2 b) { return a + (f2){-1.0f, 1.0f} * swp(b); }
__device__ __forceinline__ f2 subi(f2 a, f2 b) { return a + (f2){1.0f, -1.0f} * swp(b); }

// ---- xor-lane exchange: DPP (VALU-speed) for h in {1,2,4,8}; bpermute-based
// ---- __shfl_xor only for cross-row h in {16,32}. All 64 lanes active.
template<int CTRL>
__device__ __forceinline__ float dpp_f(float v) {
  return __int_as_float(__builtin_amdgcn_update_dpp(
      __float_as_int(v), __float_as_int(v), CTRL, 0xF, 0xF, true));
}
template<int CTRL>
__device__ __forceinline__ float dpp0_f(float v) {   // old=0, invalid lanes -> 0
  return __int_as_float(__builtin_amdgcn_update_dpp(
      0, __float_as_int(v), CTRL, 0xF, 0xF, true));
}
template<int H>
__device__ __forceinline__ float xlane(float v) {
  if constexpr (H == 1)      return dpp_f<0xB1>(v);    // quad_perm [1,0,3,2] = xor1
  else if constexpr (H == 2) return dpp_f<0x4E>(v);    // quad_perm [2,3,0,1] = xor2
  else if constexpr (H == 4) return dpp_f<0x141>(dpp_f<0x1B>(v)); // xor7 o xor3 = xor4
  else if constexpr (H == 8) return dpp_f<0x128>(v);   // row_ror:8 = xor8
  else return __shfl_xor(v, H, 64);
}
template<int H>
__device__ __forceinline__ f2 xlane2(f2 v) {
  return (f2){xlane<H>(v.x), xlane<H>(v.y)};
}
__device__ __forceinline__ f2 shfl2(f2 v, int l) {
  return (f2){__shfl(v.x, l, 64), __shfl(v.y, l, 64)};
}
__device__ __forceinline__ float bcast0(float v) {
  return __int_as_float(__builtin_amdgcn_readfirstlane(__float_as_int(v)));
}
// 64-lane sum, zero DS ops: row_shr prefix adds + row_bcast15/31.
__device__ __forceinline__ float wave_sum(float v) {
  v += dpp0_f<0x111>(v);   // row_shr:1
  v += dpp0_f<0x112>(v);   // row_shr:2
  v += dpp0_f<0x114>(v);   // row_shr:4
  v += dpp0_f<0x118>(v);   // row_shr:8
  v += dpp0_f<0x142>(v);   // row_bcast15
  v += dpp0_f<0x143>(v);   // row_bcast31 -> lane 63 holds total
  return __int_as_float(__builtin_amdgcn_readlane(__float_as_int(v), 63));
}

__device__ __forceinline__ void fft4_fwd(f2* v) {
  f2 t0 = v[0] + v[2], t1 = v[0] - v[2];
  f2 t2 = v[1] + v[3], t3 = v[1] - v[3];
  v[0] = t0 + t2; v[2] = t0 - t2;
  v[1] = subi(t1, t3);
  v[3] = addi(t1, t3);
}
__device__ __forceinline__ void fft4_inv(f2* v) {
  f2 t0 = v[0] + v[2], t1 = v[0] - v[2];
  f2 t2 = v[1] + v[3], t3 = v[1] - v[3];
  v[0] = t0 + t2; v[2] = t0 - t2;
  v[1] = addi(t1, t3);
  v[3] = subi(t1, t3);
}

// Butterfly stages with LANE-MASKED twiddles (lo lanes hold W=(1,0): no
// cndmask selects anywhere). sg = +1 lo / -1 hi.
template<int H>
__device__ __forceinline__ void fwd_stage(f2* v, float wr, f2 wn, float sg) {
#pragma unroll
  for (int b = 0; b < 4; ++b) {
    f2 p = xlane2<H>(v[b]);
    f2 t = sg * v[b] + p;          // lo: v+p ; hi: p-v
    v[b] = cmulp(t, wr, wn);       // lo: *1 ; hi: *e^{-i th}
  }
}
template<int H>
__device__ __forceinline__ void inv_stage(f2* v, float wr, f2 wn, float sg) {
#pragma unroll
  for (int b = 0; b < 4; ++b) {
    f2 u = cmulpc(v[b], wr, wn);   // lo: v ; hi: v*e^{+i th} (conj W)
    f2 p = xlane2<H>(u);
    v[b] = sg * u + p;             // lo: u+p ; hi: p-u
  }
}

// 256-point FFT: time n = 64a+lane (slot a) <-> freq k = 4*rev6(lane)+b.
__device__ __forceinline__ void fft256_fwd(f2* v,
                                           const float* twFc, const f2* twFn,
                                           const float* wrS, const f2* wnS,
                                           const float* sgS) {
  fft4_fwd(v);
#pragma unroll
  for (int b = 1; b < 4; ++b) v[b] = cmulp(v[b], twFc[b-1], twFn[b-1]);
  fwd_stage<32>(v, wrS[0], wnS[0], sgS[0]);
  fwd_stage<16>(v, wrS[1], wnS[1], sgS[1]);
  fwd_stage<8> (v, wrS[2], wnS[2], sgS[2]);
  fwd_stage<4> (v, wrS[3], wnS[3], sgS[3]);
  fwd_stage<2> (v, wrS[4], wnS[4], sgS[4]);
  fwd_stage<1> (v, wrS[5], wnS[5], sgS[5]);
}

__device__ __forceinline__ void ifft256(f2* v,
                                        const float* twFc, const f2* twFn,
                                        const float* wrS, const f2* wnS,
                                        const float* sgS) {
  inv_stage<1> (v, wrS[5], wnS[5], sgS[5]);
  inv_stage<2> (v, wrS[4], wnS[4], sgS[4]);
  inv_stage<4> (v, wrS[3], wnS[3], sgS[3]);
  inv_stage<8> (v, wrS[2], wnS[2], sgS[2]);
  inv_stage<16>(v, wrS[1], wnS[1], sgS[1]);
  inv_stage<32>(v, wrS[0], wnS[0], sgS[0]);
#pragma unroll
  for (int b = 1; b < 4; ++b) v[b] = cmulpc(v[b], twFc[b-1], twFn[b-1]);
  fft4_inv(v);
}

// Half-spectrum S[0..255] (+ real scalar S256) -> packed Z for ifft256.
__device__ __forceinline__ void half_to_z(f2* S, float S256,
                                          const float* twHc, const f2* twHn,
                                          int lane, int pl0, int plx) {
  f2 P[4];
  P[0] = shfl2(S[0], pl0);
#pragma unroll
  for (int b = 1; b < 4; ++b) P[b] = shfl2(S[4 - b], plx);
  P[0] = (lane == 0) ? (f2){S256, 0.0f} : P[0];
#pragma unroll
  for (int b = 0; b < 4; ++b) {
    f2 cP = conjf2(P[b]);
    f2 A = 0.5f * (S[b] + cP);
    f2 B = 0.5f * (S[b] - cP);
    f2 Bt = cmulp(B, twHc[b], twHn[b]);   // B * e^{+i th}
    S[b] = addi(A, Bt);
  }
}

// Per-bin mode update exploiting Hermitian symmetry (no cross-lane ops).
__device__ __forceinline__ void mode_update4(const f2* X, const f2* V, f2* U,
                                             const float* lam1, const float* lam2,
                                             float om, float f0) {
#pragma unroll
  for (int b = 0; b < 4; ++b) {
    float f = f0 + (float)b * (1.0f / 512.0f);
    float dfp = f - om;
    float dfm = f + om;
    float gp = __builtin_amdgcn_rcpf(fmaf(1600.0f * dfp, dfp, 1.0f));
    float gm = __builtin_amdgcn_rcpf(fmaf(1600.0f * dfm, dfm, 1.0f));
    float gs = 0.5f * (gp + gm);
    f2 D = X[b] - V[b];
    float lt = 0.25f * fmaf(lam1[b], gp, lam2[b] * gm);
    U[b] = gs * D + (f2){lt, 0.0f};
  }
}

// One wave per (b,d) sequence. Round-16 verified best (239 us total):
// DPP wave-sum (zero DS), xor4 via 2xDPP, rcp omega divide, lane-masked
// twiddles, pk-packed complex math, fused order+swap+zero epilogue kernel.
// NOTE (r17): in-kernel spin-sync fusion REGRESSED (+17 us straggler wait);
// the tiny epi dispatch (~5 us, HBM-bound) is cheaper. Keep two kernels.
__global__ __attribute__((amdgpu_flat_work_group_size(256, 256),
                          amdgpu_waves_per_eu(4, 4),
                          amdgpu_num_vgpr(96)))
void vmd_kernel(const float* __restrict__ x, float* __restrict__ out,
                float* __restrict__ ws) {
  __shared__ float stage[4 * 512];    // [seq][n]; x resident during loop, reused for out
  __shared__ float ldsLam[4 * 512];   // psi-permuted lambda per wave

  const int tid = threadIdx.x;
  const int wv = tid >> 6;
  const int lane = tid & 63;
  const int w = (blockIdx.x >> 3) + ((blockIdx.x & 7) << 7);   // XCD swizzle
  const int g = 4 * w + wv;
  const int bb = w >> 5;
  const int d0 = (4 * w) & 127;
  const int base4 = bb * 16384 + (d0 >> 2);
  float* lamLds = ldsLam + wv * 512;
  f2* stg2 = (f2*)stage + wv * 256;   // packed (even,odd) pair view of this seq

  const int rev = (int)(__brev((unsigned)lane) >> 26);           // rev6(lane)
  const float f0 = (float)rev * (1.0f / 128.0f);
  const int plx = lane ^ 63;
  const int pl0 = (int)(__brev((unsigned)((64 - rev) & 63)) >> 26);

  // Stage twiddles, lane-masked: lo lanes = identity (wr=1, wn=0).
  float wrS[6], sgS[6]; f2 wnS[6];
#pragma unroll
  for (int s = 0; s < 6; ++s) {
    const int h = 32 >> s;
    const bool hi = (lane & h) != 0;
    float th = (float)(lane & (h - 1)) * (3.14159265358979323846f / (float)h);
    float sn, cs; sincosf(th, &sn, &cs);
    wrS[s] = hi ? cs : 1.0f;                        // W = e^{-i th}
    wnS[s] = hi ? (f2){sn, -sn} : (f2){0.0f, 0.0f};
    sgS[s] = hi ? -1.0f : 1.0f;
  }
  float twFc[3]; f2 twFn[3];
#pragma unroll
  for (int b = 1; b < 4; ++b) {
    float th = (float)(lane * b) * 0.02454369260617026f;   // 2pi/256, e^{-i th}
    float sn, cs; sincosf(th, &sn, &cs);
    twFc[b-1] = cs; twFn[b-1] = (f2){sn, -sn};
  }
  float twHc[4]; f2 twHn[4];
#pragma unroll
  for (int b = 0; b < 4; ++b) {
    float th = (float)(4 * rev + b) * 0.01227184630308513f; // 2pi/512, e^{+i th}
    float sn, cs; sincosf(th, &sn, &cs);
    twHc[b] = cs; twHn[b] = (f2){-sn, sn};
  }

  // ---- load x: float4 (n, d0..d0+3) -> stage[seq][n]; zero lambda ----
  {
    const float4* x4 = (const float4*)x;
    float4 va = x4[base4 + tid * 32];
    float4 vb = x4[base4 + (tid + 256) * 32];
    stage[tid]        = va.x; stage[512 + tid]        = va.y;
    stage[1024 + tid] = va.z; stage[1536 + tid]       = va.w;
    stage[tid + 256]        = vb.x; stage[512 + tid + 256]  = vb.y;
    stage[1024 + tid + 256] = vb.z; stage[1536 + tid + 256] = vb.w;
#pragma unroll
    for (int j = 0; j < 8; ++j) ldsLam[tid * 8 + j] = 0.0f;
  }
  __syncthreads();

  // ---- initial FFT input straight from LDS (x stays resident in stage) ----
  f2 z[4];
#pragma unroll
  for (int a = 0; a < 4; ++a) z[a] = stg2[64 * a + lane];
  fft256_fwd(z, twFc, twFn, wrS, wnS, sgS);
  f2 X[4];
  float X256;
  {
    f2 P[4];
    P[0] = shfl2(z[0], pl0);
#pragma unroll
    for (int b = 1; b < 4; ++b) P[b] = shfl2(z[4 - b], plx);
    X256 = bcast0(z[0].x - z[0].y);
#pragma unroll
    for (int b = 0; b < 4; ++b) {
      f2 cP = conjf2(P[b]);
      f2 E = 0.5f * (z[b] + cP);
      f2 O = 0.5f * (f2){1.0f, -1.0f} * swp(z[b] - cP);   // -i*(z-cP)/2
      X[b] = E + cmulpc(O, twHc[b], twHn[b]);             // O * e^{-i th}
    }
  }

  f2 U0[4], U1[4], lam[4];
#pragma unroll
  for (int b = 0; b < 4; ++b) {
    U0[b] = (f2){0.0f, 0.0f}; U1[b] = (f2){0.0f, 0.0f};
    lam[b] = (f2){0.0f, 0.0f};
  }
  float U0_256 = 0.0f, U1_256 = 0.0f;
  float om0 = 0.0f, om1 = 0.0f;

  const int psiE = 256 * (lane & 1) + (lane >> 1);   // lambda write base

#pragma unroll 1
  for (int it = 0; it < 50; ++it) {
    float lam1[4], lam2[4];
#pragma unroll
    for (int b = 0; b < 4; ++b) lam1[b] = lamLds[128 * b + 64 + rev];
    lam2[0] = lamLds[64 - rev];
#pragma unroll
    for (int b = 1; b < 4; ++b) lam2[b] = lamLds[128 * (4 - b) + 63 - rev];
    float lam0 = lamLds[0];

    mode_update4(X, U1, U0, lam1, lam2, om0, f0);
    {
      float dm = 0.5f + om0;
      float gg = __builtin_amdgcn_rcpf(fmaf(1600.0f * dm, dm, 1.0f));
      U0_256 = (X256 - U1_256 + 0.5f * lam0) * gg;
    }
    mode_update4(X, U0, U1, lam1, lam2, om1, f0);
    {
      float dm = 0.5f + om1;
      float gg = __builtin_amdgcn_rcpf(fmaf(1600.0f * dm, dm, 1.0f));
      U1_256 = (X256 - U0_256 + 0.5f * lam0) * gg;
    }

    // omega: per-bin accumulate, then pure-DPP wave sums (zero DS ops)
    f2 s0 = (f2){0.0f, 0.0f}, s1 = (f2){0.0f, 0.0f};
#pragma unroll
    for (int b = 0; b < 4; ++b) {
      float f = f0 + (float)b * (1.0f / 512.0f);
      float p0 = fmaf(U0[b].x, U0[b].x, U0[b].y * U0[b].y);
      float p1 = fmaf(U1[b].x, U1[b].x, U1[b].y * U1[b].y);
      s0 = s0 + (f2){f * p0, p0};
      s1 = s1 + (f2){f * p1, p1};
    }
    float n0 = wave_sum(s0.x), d0s = wave_sum(s0.y);
    float n1 = wave_sum(s1.x), d1s = wave_sum(s1.y);
    om0 = n0 * __builtin_amdgcn_rcpf(d0s + 1e-7f);
    om1 = n1 * __builtin_amdgcn_rcpf(d1s + 1e-7f);

    if (it < 49) {   // last iteration's lambda is never consumed
#pragma unroll
      for (int b = 0; b < 4; ++b) z[b] = U0[b] + U1[b];
      float S256 = U0_256 + U1_256;
      half_to_z(z, S256, twHc, twHn, lane, pl0, plx);
      ifft256(z, twFc, twFn, wrS, wnS, sgS);
#pragma unroll
      for (int a = 0; a < 4; ++a) {
        f2 xa = stg2[64 * a + lane];               // x from LDS
        lam[a] = lam[a] + 0.001f * (xa - z[a] * (1.0f / 256.0f));
        lamLds[psiE + 32 * a]       = lam[a].x;
        lamLds[psiE + 32 * a + 128] = lam[a].y;
      }
      asm volatile("s_waitcnt lgkmcnt(0)" ::: "memory");
    }
  }

  // ---- final modes: half->z, ifft256, pack to stage, float4 stores ----
  float4* o4 = (float4*)out;
#pragma unroll
  for (int b = 0; b < 4; ++b) z[b] = U0[b];
  half_to_z(z, U0_256, twHc, twHn, lane, pl0, plx);
  ifft256(z, twFc, twFn, wrS, wnS, sgS);
  __syncthreads();   // all waves done reading x from stage
#pragma unroll
  for (int a = 0; a < 4; ++a) stg2[64 * a + lane] = z[a] * (1.0f / 256.0f);
  __syncthreads();
#pragma unroll
  for (int r = 0; r < 2; ++r) {
    const int n = tid + r * 256;
    float4 v;
    v.x = stage[n]; v.y = stage[512 + n]; v.z = stage[1024 + n]; v.w = stage[1536 + n];
    o4[FIELD / 4 + base4 + n * 32] = v;
  }
  __syncthreads();
#pragma unroll
  for (int b = 0; b < 4; ++b) z[b] = U1[b];
  half_to_z(z, U1_256, twHc, twHn, lane, pl0, plx);
  ifft256(z, twFc, twFn, wrS, wnS, sgS);
#pragma unroll
  for (int a = 0; a < 4; ++a) stg2[64 * a + lane] = z[a] * (1.0f / 256.0f);
  __syncthreads();
#pragma unroll
  for (int r = 0; r < 2; ++r) {
    const int n = tid + r * 256;
    float4 v;
    v.x = stage[n]; v.y = stage[512 + n]; v.z = stage[1024 + n]; v.w = stage[1536 + n];
    o4[2 * FIELD / 4 + base4 + n * 32] = v;
  }

  if (lane == 0) {
    ws[g] = om0;             // omega staging in workspace (read-only for epi)
    ws[NSEQ + g] = om1;
  }
}

// Fused epilogue: per-batch flag recomputed per block (64 ws reads + wave
// reduce), trend slice zeroed, period/res conditionally swapped.
__global__ __launch_bounds__(256) void epi_kernel(float* __restrict__ out,
                                                  const float* __restrict__ ws) {
  const int tid = threadIdx.x;
  const int blk = blockIdx.x;          // 0..2047; 64 blocks per batch
  const int bb = blk >> 6;
  __shared__ float flagS;
  if (tid < 64) {
    float o0 = ws[bb * 128 + tid] + ws[bb * 128 + 64 + tid];
    float o1 = ws[NSEQ + bb * 128 + tid] + ws[NSEQ + bb * 128 + 64 + tid];
#pragma unroll
    for (int off = 32; off >= 1; off >>= 1) {
      o0 += __shfl_xor(o0, off, 64);
      o1 += __shfl_xor(o1, off, 64);
    }
    if (tid == 0) flagS = (o0 > o1) ? 1.0f : 0.0f;   // swap iff mean0 > mean1
  }
  __syncthreads();
  const bool sw = flagS > 0.5f;
  float4* o4 = (float4*)out;
  const int i = blk * 256 + tid;       // float4 index within trend field
  o4[i] = (float4){0.0f, 0.0f, 0.0f, 0.0f};
  if (sw) {
    float4 p = o4[FIELD / 4 + i];
    float4 r = o4[2 * FIELD / 4 + i];
    o4[FIELD / 4 + i] = r;
    o4[2 * FIELD / 4 + i] = p;
  }
}

extern "C" void kernel_launch(void* const* d_in, const int* in_sizes, int n_in,
                              void* d_out, int out_size, void* d_ws, size_t ws_size,
                              hipStream_t stream) {
  (void)in_sizes; (void)n_in; (void)ws_size; (void)out_size;
  const float* x = (const float*)d_in[0];
  float* out = (float*)d_out;
  float* ws = (float*)d_ws;
  vmd_kernel<<<NSEQ / 4, 256, 0, stream>>>(x, out, ws);
  epi_kernel<<<FIELD / 1024, 256, 0, stream>>>(out, ws);
}